// Round 5
// baseline (311.931 us; speedup 1.0000x reference)
//
#include <hip/hip_runtime.h>
#include <hip/hip_bf16.h>

// LinearAttention collapse (all I/O fp32; x->bf16 only inside the MFMA GEMM):
//   out[b] = x[b] @ W_eff[b] + b_eff[b]
//   W_eff[b] = Wq@Wo + Wk@(diag(aw[b]) * (Wp@Wo))          [256 x 64]
//   b_eff[b] = (bq+bp)@Wo + bo + bk@(diag(aw[b])*(Wp@Wo))  [64]
//   aw[b]    = s_x[b]@Wq + t_sum[b]*bq                     [512]
//   s_x[b]   = sum_n t[b,n]*x[b,n,:],  t_sum[b] = sum_n t[b,n]
//   t[b,n]   = SCALE*(x[b,n].(Wq@qw) + bq.qw)
//
// R5: cross-round ledger shows aw+weff still ~98us and prep ~8us, all
//     latency-bound at low occupancy (weff: 512 blocks = 2/CU = 2 waves/SIMD,
//     512-deep L2-latency chains). Fix = 4x TLP + 4x shorter chains:
//   - k_weff: grid (256,8)=2048 blocks (8/CU); 1 c/block, d split 4-way
//     (128 iters/thread) + LDS reduce
//   - k_aw:   grid (8,8)=64 blocks; 64 d/block, c split 4-way + LDS reduce
//   - k_prep: 1 block/output-row (770 blocks); e split 4-way + LDS reduce
// k_phase1 / k_out unchanged (R2 ledger: prep+phase1+out+gaps ~ 46us total).

#define NN 16384
#define CC 256
#define DD 512
#define HH 64
#define SCALE_F 0.125f

// float-offset workspace layout
#define OFF_SX    0        // [8][256]
#define OFF_TSUM  2048     // [8]
#define OFF_WQQ   2056     // [256]
#define OFF_BQQ   2312     // [1]
#define OFF_WPWO  2320     // [512][64] fp32
#define OFF_WQWO  35088    // [256][64] fp32
#define OFF_CBIAS 51472    // [64]
#define OFF_BEFF  51536    // [8][64]
#define OFF_WEFFT 52048    // bf16 [8][64][256] (byte ofs 208192, 16B aligned)
#define OFF_AW    117584   // [8][512] fp32

typedef unsigned short ushort_t;
typedef __attribute__((ext_vector_type(8))) short short8;     // 8 bf16
typedef __attribute__((ext_vector_type(4))) float floatx4;

__device__ __forceinline__ unsigned short f2bf(float f) {
    __hip_bfloat16 h = __float2bfloat16(f);
    return __builtin_bit_cast(unsigned short, h);
}

// ---------------- K0: batch-independent weight folding + zero accumulators ----
// grid 770: bid<512 -> WpWo row d=bid ; bid<768 -> WqWo row c=bid-512 ;
//           768 -> wqq/bqq ; 769 -> cbias + zero s_x/t_sum
// Row kernels: h = tid&63, part = tid>>6 covers 128 e's; LDS 4-way reduce.
__global__ __launch_bounds__(256) void k_prep(
    const float* __restrict__ Wq, const float* __restrict__ bq,
    const float* __restrict__ qw, const float* __restrict__ Wp,
    const float* __restrict__ bp, const float* __restrict__ Wo,
    const float* __restrict__ bo, float* __restrict__ ws)
{
    __shared__ float lds[520];
    const int tid = threadIdx.x;
    const int bid = blockIdx.x;

    if (bid < 768) {
        const bool is_wp = (bid < 512);
        const int row = is_wp ? bid : (bid - 512);
        const float* src = is_wp ? (Wp + (size_t)row * 512)
                                 : (Wq + (size_t)row * 512);
        const int h = tid & 63, part = tid >> 6;
        const int e0 = part * 128;
        float a0 = 0.f, a1 = 0.f, a2 = 0.f, a3 = 0.f;
        for (int e = e0; e < e0 + 128; e += 4) {
            a0 = fmaf(src[e + 0], Wo[(e + 0) * 64 + h], a0);
            a1 = fmaf(src[e + 1], Wo[(e + 1) * 64 + h], a1);
            a2 = fmaf(src[e + 2], Wo[(e + 2) * 64 + h], a2);
            a3 = fmaf(src[e + 3], Wo[(e + 3) * 64 + h], a3);
        }
        lds[tid] = ((a0 + a1) + (a2 + a3));
        __syncthreads();
        if (tid < 64) {
            const float v = lds[tid] + lds[64 + tid] + lds[128 + tid] + lds[192 + tid];
            const int off = is_wp ? (OFF_WPWO + row * 64) : (OFF_WQWO + row * 64);
            ws[off + tid] = v;
        }
    } else if (bid == 768) {
        // wqq = Wq @ qw ; bqq = bq . qw (wave-reduced)
        float* lb = lds + 512;
        for (int i = tid; i < 512; i += 256) lds[i] = qw[i];
        if (tid == 0) *lb = 0.f;
        __syncthreads();
        const float* wr = Wq + (size_t)tid * 512;
        float a0 = 0.f, a1 = 0.f, a2 = 0.f, a3 = 0.f;
        for (int d = 0; d < 512; d += 4) {
            a0 = fmaf(wr[d + 0], lds[d + 0], a0);
            a1 = fmaf(wr[d + 1], lds[d + 1], a1);
            a2 = fmaf(wr[d + 2], lds[d + 2], a2);
            a3 = fmaf(wr[d + 3], lds[d + 3], a3);
        }
        ws[OFF_WQQ + tid] = ((a0 + a1) + (a2 + a3));
        float pb = fmaf(bq[tid], lds[tid], bq[tid + 256] * lds[tid + 256]);
#pragma unroll
        for (int m = 1; m < 64; m <<= 1) pb += __shfl_xor(pb, m);
        if ((tid & 63) == 0) atomicAdd(lb, pb);
        __syncthreads();
        if (tid == 0) ws[OFF_BQQ] = *lb;
    } else {
        // cbias[h] = (bq+bp)@Wo + bo ; 4 partials per h, LDS-reduced
        const int h = tid & 63, part = tid >> 6;
        float acc = 0.f;
        for (int d = part * 128; d < part * 128 + 128; ++d)
            acc = fmaf(bq[d] + bp[d], Wo[d * 64 + h], acc);
        lds[tid] = acc;
        __syncthreads();
        if (tid < 64)
            ws[OFF_CBIAS + tid] = bo[tid] + lds[tid] + lds[64 + tid] +
                                  lds[128 + tid] + lds[192 + tid];
        // zero s_x + t_sum
        for (int i = tid; i < 2056; i += 256) ws[OFF_SX + i] = 0.f;
    }
}

// ---------------- K1: stream x, reduce s_x / t_sum -----------------------
// 16-lane groups: lane owns 16 cols (4x floatx4); row-dot reduce = 4 shfl_xor
// within the quad's 16 lanes.
__global__ __launch_bounds__(256) void k_phase1(
    const float* __restrict__ x, float* __restrict__ ws)
{
    const int tid  = threadIdx.x;
    const int lane = tid & 63;
    const int wave = tid >> 6;
    const int quad = lane >> 4;
    const int l15  = lane & 15;
    __shared__ float lacc[256];
    __shared__ float ltsum;

    floatx4 wv[4];
#pragma unroll
    for (int j = 0; j < 4; ++j)
        wv[j] = *(const floatx4*)(ws + OFF_WQQ + j * 64 + l15 * 4);
    const float bqq = ws[OFF_BQQ];

    const int vb = blockIdx.x;
    const int b = vb >> 7;
    const int rbase = (vb & 127) * 128;
    lacc[tid] = 0.f;
    if (tid == 0) ltsum = 0.f;
    __syncthreads();

    const float* xb = x + (size_t)b * NN * CC;
    const int r0 = rbase + wave * 32 + quad;   // rows r0 + 4*it
    floatx4 accs[4];
#pragma unroll
    for (int j = 0; j < 4; ++j)
#pragma unroll
        for (int k = 0; k < 4; ++k) accs[j][k] = 0.f;
    float ts = 0.f;

#pragma unroll 2
    for (int it = 0; it < 8; ++it) {
        const float* xr = xb + (size_t)(r0 + it * 4) * CC + l15 * 4;
        const floatx4 x0 = *(const floatx4*)(xr);
        const floatx4 x1 = *(const floatx4*)(xr + 64);
        const floatx4 x2 = *(const floatx4*)(xr + 128);
        const floatx4 x3 = *(const floatx4*)(xr + 192);
        float p = 0.f;
#pragma unroll
        for (int k = 0; k < 4; ++k) {
            p = fmaf(x0[k], wv[0][k], p);
            p = fmaf(x1[k], wv[1][k], p);
            p = fmaf(x2[k], wv[2][k], p);
            p = fmaf(x3[k], wv[3][k], p);
        }
        p += __shfl_xor(p, 1);
        p += __shfl_xor(p, 2);
        p += __shfl_xor(p, 4);
        p += __shfl_xor(p, 8);
        const float t = SCALE_F * (p + bqq);
        ts += t;
#pragma unroll
        for (int k = 0; k < 4; ++k) {
            accs[0][k] = fmaf(t, x0[k], accs[0][k]);
            accs[1][k] = fmaf(t, x1[k], accs[1][k]);
            accs[2][k] = fmaf(t, x2[k], accs[2][k]);
            accs[3][k] = fmaf(t, x3[k], accs[3][k]);
        }
    }

    // cross-quad reduce (xor 16, 32), quad0 lanes accumulate into LDS
#pragma unroll
    for (int j = 0; j < 4; ++j)
#pragma unroll
        for (int k = 0; k < 4; ++k) {
            float v = accs[j][k];
            v += __shfl_xor(v, 16);
            v += __shfl_xor(v, 32);
            if (quad == 0) atomicAdd(&lacc[j * 64 + l15 * 4 + k], v);
        }
    if (l15 == 0) atomicAdd(&ltsum, ts);
    __syncthreads();
    atomicAdd(&ws[OFF_SX + b * 256 + tid], lacc[tid]);
    if (tid == 0) atomicAdd(&ws[OFF_TSUM + b], ltsum);
}

// ---------------- K2a: aw[b,d] = s_x[b]@Wq[:,d] + tsum[b]*bq[d] ------------
// grid (8, 8): blockIdx.x = 64-d chunk, blockIdx.y = batch.
// d = bx*64 + (tid&63); part = tid>>6 covers 64 c's; LDS 4-way reduce.
__global__ __launch_bounds__(256) void k_aw(
    const float* __restrict__ Wq, const float* __restrict__ bq,
    float* __restrict__ ws)
{
    const int tid = threadIdx.x;
    const int b = blockIdx.y;
    const int dl = tid & 63, part = tid >> 6;
    const int d = blockIdx.x * 64 + dl;
    __shared__ float lsx[256];
    __shared__ float lred[256];
    __shared__ float lts;
    lsx[tid] = ws[OFF_SX + b * 256 + tid];
    if (tid == 0) lts = ws[OFF_TSUM + b];
    __syncthreads();

    const int c0 = part * 64;
    float a0 = 0.f, a1 = 0.f, a2 = 0.f, a3 = 0.f;
    for (int c = c0; c < c0 + 64; c += 4) {
        a0 = fmaf(lsx[c + 0], Wq[(c + 0) * 512 + d], a0);
        a1 = fmaf(lsx[c + 1], Wq[(c + 1) * 512 + d], a1);
        a2 = fmaf(lsx[c + 2], Wq[(c + 2) * 512 + d], a2);
        a3 = fmaf(lsx[c + 3], Wq[(c + 3) * 512 + d], a3);
    }
    lred[tid] = ((a0 + a1) + (a2 + a3));
    __syncthreads();
    if (tid < 64) {
        const float s = lred[tid] + lred[64 + tid] + lred[128 + tid] + lred[192 + tid];
        const int dd = blockIdx.x * 64 + tid;
        ws[OFF_AW + b * 512 + dd] = lts * bq[dd] + s;
    }
}

// ---------------- K2b: W_effT (bf16) + b_eff -------------------------------
// grid (256, 8): blockIdx.x = c, blockIdx.y = batch. 8 blocks/CU.
// h = tid&63, part = tid>>6 covers 128 d's; LDS 4-way reduce.
__global__ __launch_bounds__(256) void k_weff(
    const float* __restrict__ Wk, const float* __restrict__ bk,
    float* __restrict__ ws)
{
    const int tid = threadIdx.x;
    const int b = blockIdx.y;
    const int c = blockIdx.x;
    const int h = tid & 63, part = tid >> 6;
    __shared__ float lred[256];

    const float* law = ws + OFF_AW + (size_t)b * 512;
    const float* wkr = Wk + (size_t)c * 512;
    const float* wp  = ws + OFF_WPWO;

    const int d0 = part * 128;
    float a0 = 0.f, a1 = 0.f, a2 = 0.f, a3 = 0.f;
    for (int d = d0; d < d0 + 128; d += 4) {
        a0 = fmaf(wkr[d + 0] * law[d + 0], wp[(d + 0) * 64 + h], a0);
        a1 = fmaf(wkr[d + 1] * law[d + 1], wp[(d + 1) * 64 + h], a1);
        a2 = fmaf(wkr[d + 2] * law[d + 2], wp[(d + 2) * 64 + h], a2);
        a3 = fmaf(wkr[d + 3] * law[d + 3], wp[(d + 3) * 64 + h], a3);
    }
    lred[tid] = ((a0 + a1) + (a2 + a3));
    __syncthreads();
    if (tid < 64) {
        const float v = ws[OFF_WQWO + c * 64 + tid] + lred[tid] +
                        lred[64 + tid] + lred[128 + tid] + lred[192 + tid];
        ushort_t* wt = (ushort_t*)(ws + OFF_WEFFT) + (size_t)b * (HH * CC);
        wt[(size_t)tid * CC + c] = f2bf(v);
    }

    // b_eff (blocks with c==0 only; block-uniform branch)
    if (c == 0) {
        __syncthreads();   // protect lred reuse (WAR vs reduce-read above)
        float a = 0.f;
        for (int d = d0; d < d0 + 128; ++d)
            a = fmaf(bk[d] * law[d], wp[d * 64 + h], a);
        lred[tid] = a;
        __syncthreads();
        if (tid < 64)
            ws[OFF_BEFF + b * 64 + tid] = ws[OFF_CBIAS + tid] + lred[tid] +
                lred[64 + tid] + lred[128 + tid] + lred[192 + tid];
    }
}

// ---------------- K3: out = x @ W_eff + b_eff  (MFMA bf16) -----------------
// grid 1024: vb>>7 = batch, vb&127 = row-tile base; each block computes
// TWO 64-row tiles per single W_effT staging; s=0 A-fragments loaded
// before the staging barrier so HBM latency hides under LDS staging.
__global__ __launch_bounds__(256) void k_out(
    const float* __restrict__ x, const float* __restrict__ ws,
    float* __restrict__ out)
{
    const int tid  = threadIdx.x;
    const int lane = tid & 63;
    const int wave = tid >> 6;
    const int quad = lane >> 4;
    const int l15  = lane & 15;
    // Stage W_effT[b] in LDS, stride 264 (pad 8) -> 2-way-free ds_read_b128
    __shared__ __align__(16) ushort_t lwt[64 * 264];

    const int vb = blockIdx.x;
    const int b = vb >> 7;
    const int rt0 = vb & 127;

    // ---- s=0 A-fragments first (no LDS dependency) ----
    const int row0_0 = rt0 * 64 + wave * 16;
    const float* xr0 = x + ((size_t)b * NN + row0_0 + l15) * CC + quad * 8;
    short8 afrag0[8];
#pragma unroll
    for (int kk = 0; kk < 8; ++kk) {
        const floatx4 u0 = *(const floatx4*)(xr0 + kk * 32);
        const floatx4 u1 = *(const floatx4*)(xr0 + kk * 32 + 4);
        short8 t;
        t[0] = (short)f2bf(u0[0]); t[1] = (short)f2bf(u0[1]);
        t[2] = (short)f2bf(u0[2]); t[3] = (short)f2bf(u0[3]);
        t[4] = (short)f2bf(u1[0]); t[5] = (short)f2bf(u1[1]);
        t[6] = (short)f2bf(u1[2]); t[7] = (short)f2bf(u1[3]);
        afrag0[kk] = t;
    }

    // ---- stage W_effT ----
    const ushort_t* wt = (const ushort_t*)(ws + OFF_WEFFT) + (size_t)b * (HH * CC);
    for (int o = tid; o < 2048; o += 256) {
        const int h = o >> 5, seg = o & 31;
        *(short8*)(lwt + h * 264 + seg * 8) = *(const short8*)(wt + h * 256 + seg * 8);
    }
    __syncthreads();

    const float* beff = ws + OFF_BEFF + b * 64;
    float bias[4];
#pragma unroll
    for (int ht = 0; ht < 4; ++ht) bias[ht] = beff[ht * 16 + l15];

    // ---- s=0 MFMA + store ----
    {
        floatx4 acc[4];
#pragma unroll
        for (int ht = 0; ht < 4; ++ht)
#pragma unroll
            for (int r = 0; r < 4; ++r) acc[ht][r] = 0.f;
#pragma unroll
        for (int kk = 0; kk < 8; ++kk)
#pragma unroll
            for (int ht = 0; ht < 4; ++ht) {
                const short8 bf =
                    *(const short8*)(lwt + (ht * 16 + l15) * 264 + quad * 8 + kk * 32);
                acc[ht] = __builtin_amdgcn_mfma_f32_16x16x32_bf16(
                    afrag0[kk], bf, acc[ht], 0, 0, 0);
            }
#pragma unroll
        for (int ht = 0; ht < 4; ++ht) {
            const int h = ht * 16 + l15;
#pragma unroll
            for (int r = 0; r < 4; ++r) {
                const int row = row0_0 + quad * 4 + r;
                out[((size_t)b * NN + row) * HH + h] = acc[ht][r] + bias[ht];
            }
        }
    }

    // ---- s=1: load, convert, MFMA, store ----
    {
        const int row0_1 = (rt0 + 128) * 64 + wave * 16;
        const float* xr1 = x + ((size_t)b * NN + row0_1 + l15) * CC + quad * 8;
        short8 afrag1[8];
#pragma unroll
        for (int kk = 0; kk < 8; ++kk) {
            const floatx4 u0 = *(const floatx4*)(xr1 + kk * 32);
            const floatx4 u1 = *(const floatx4*)(xr1 + kk * 32 + 4);
            short8 t;
            t[0] = (short)f2bf(u0[0]); t[1] = (short)f2bf(u0[1]);
            t[2] = (short)f2bf(u0[2]); t[3] = (short)f2bf(u0[3]);
            t[4] = (short)f2bf(u1[0]); t[5] = (short)f2bf(u1[1]);
            t[6] = (short)f2bf(u1[2]); t[7] = (short)f2bf(u1[3]);
            afrag1[kk] = t;
        }
        floatx4 acc[4];
#pragma unroll
        for (int ht = 0; ht < 4; ++ht)
#pragma unroll
            for (int r = 0; r < 4; ++r) acc[ht][r] = 0.f;
#pragma unroll
        for (int kk = 0; kk < 8; ++kk)
#pragma unroll
            for (int ht = 0; ht < 4; ++ht) {
                const short8 bf =
                    *(const short8*)(lwt + (ht * 16 + l15) * 264 + quad * 8 + kk * 32);
                acc[ht] = __builtin_amdgcn_mfma_f32_16x16x32_bf16(
                    afrag1[kk], bf, acc[ht], 0, 0, 0);
            }
#pragma unroll
        for (int ht = 0; ht < 4; ++ht) {
            const int h = ht * 16 + l15;
#pragma unroll
            for (int r = 0; r < 4; ++r) {
                const int row = row0_1 + quad * 4 + r;
                out[((size_t)b * NN + row) * HH + h] = acc[ht][r] + bias[ht];
            }
        }
    }
}

extern "C" void kernel_launch(void* const* d_in, const int* in_sizes, int n_in,
                              void* d_out, int out_size, void* d_ws, size_t ws_size,
                              hipStream_t stream) {
    const float* x  = (const float*)d_in[0];
    const float* Wq = (const float*)d_in[1];
    const float* bq = (const float*)d_in[2];
    const float* Wk = (const float*)d_in[3];
    const float* bk = (const float*)d_in[4];
    const float* qw = (const float*)d_in[5];
    const float* Wp = (const float*)d_in[6];
    const float* bp = (const float*)d_in[7];
    const float* Wo = (const float*)d_in[8];
    const float* bo = (const float*)d_in[9];
    float* ws  = (float*)d_ws;
    float* out = (float*)d_out;

    hipLaunchKernelGGL(k_prep,   dim3(770),     dim3(256), 0, stream,
                       Wq, bq, qw, Wp, bp, Wo, bo, ws);
    hipLaunchKernelGGL(k_phase1, dim3(1024),    dim3(256), 0, stream, x, ws);
    hipLaunchKernelGGL(k_aw,     dim3(8, 8),    dim3(256), 0, stream, Wq, bq, ws);
    hipLaunchKernelGGL(k_weff,   dim3(256, 8),  dim3(256), 0, stream, Wk, bk, ws);
    hipLaunchKernelGGL(k_out,    dim3(1024),    dim3(256), 0, stream, x, ws, out);
}

// Round 6
// 310.561 us; speedup vs baseline: 1.0044x; 1.0044x over previous
//
#include <hip/hip_runtime.h>
#include <hip/hip_bf16.h>

// LinearAttention collapse (all I/O fp32; x->bf16 only inside the MFMA GEMM):
//   out[b] = x[b] @ W_eff[b] + b_eff[b]
//   W_eff[b] = Wq@Wo + Wk@(diag(aw[b]) * (Wp@Wo))          [256 x 64]
//   b_eff[b] = (bq+bp)@Wo + bo + bk@(diag(aw[b])*(Wp@Wo))  [64]
//   aw[b]    = s_x[b]@Wq + t_sum[b]*bq                     [512]
//   s_x[b]   = sum_n t[b,n]*x[b,n,:],  t_sum[b] = sum_n t[b,n]
//   t[b,n]   = SCALE*(x[b,n].(Wq@qw) + bq.qw)
//
// R6: measurement round + fix. aw/weff are idempotent -> launched TWICE so
//     Δdur attributes their true cost (family ≈ (dur-206)/2). Changes:
//   - k_weff v2: h-vectorized. thread=(hq=tid&15 -> float4 of 4 h's,
//     part=tid>>4 -> 32-d slice). 4x fewer VMEM instrs, all wp reads are
//     full 256B wave-lines; 16-part LDS tree reduce; b_eff in c==0 blocks.
//   - k_out reverted to R2/R3 version (R4's A-frag hoist = un-isolated
//     VGPR/occupancy risk).
//   - prep = R4's 195-block version; aw = R5's 64-block version (proven).

#define NN 16384
#define CC 256
#define DD 512
#define HH 64
#define SCALE_F 0.125f

// float-offset workspace layout
#define OFF_SX    0        // [8][256]
#define OFF_TSUM  2048     // [8]
#define OFF_WQQ   2056     // [256]
#define OFF_BQQ   2312     // [1]
#define OFF_WPWO  2320     // [512][64] fp32
#define OFF_WQWO  35088    // [256][64] fp32
#define OFF_CBIAS 51472    // [64]
#define OFF_BEFF  51536    // [8][64]
#define OFF_WEFFT 52048    // bf16 [8][64][256] (byte ofs 208192, 16B aligned)
#define OFF_AW    117584   // [8][512] fp32

typedef unsigned short ushort_t;
typedef __attribute__((ext_vector_type(8))) short short8;     // 8 bf16
typedef __attribute__((ext_vector_type(4))) float floatx4;

__device__ __forceinline__ unsigned short f2bf(float f) {
    __hip_bfloat16 h = __float2bfloat16(f);
    return __builtin_bit_cast(unsigned short, h);
}

// ---------------- K0: batch-independent weight folding + zero accumulators ----
// grid 195: 0..127 WpWo (4 rows ea), 128..191 WqWo (4 rows ea),
//           192 wqq/bqq, 193 cbias, 194 zero s_x/t_sum
__global__ __launch_bounds__(256) void k_prep(
    const float* __restrict__ Wq, const float* __restrict__ bq,
    const float* __restrict__ qw, const float* __restrict__ Wp,
    const float* __restrict__ bp, const float* __restrict__ Wo,
    const float* __restrict__ bo, float* __restrict__ ws)
{
    __shared__ float lds[2056];
    const int tid = threadIdx.x;
    const int bid = blockIdx.x;

    if (bid < 128) {
        const int d0 = bid * 4;
        for (int i = tid; i < 2048; i += 256) lds[i] = Wp[d0 * 512 + i];
        __syncthreads();
        const int dl = tid >> 6, h = tid & 63;
        float acc = 0.f;
        for (int e = 0; e < 512; ++e)
            acc = fmaf(lds[dl * 512 + e], Wo[e * 64 + h], acc);
        ws[OFF_WPWO + (d0 + dl) * 64 + h] = acc;
    } else if (bid < 192) {
        const int c0 = (bid - 128) * 4;
        for (int i = tid; i < 2048; i += 256) lds[i] = Wq[c0 * 512 + i];
        __syncthreads();
        const int cl = tid >> 6, h = tid & 63;
        float acc = 0.f;
        for (int e = 0; e < 512; ++e)
            acc = fmaf(lds[cl * 512 + e], Wo[e * 64 + h], acc);
        ws[OFF_WQWO + (c0 + cl) * 64 + h] = acc;
    } else if (bid == 192) {
        // wqq = Wq @ qw ; bqq = bq . qw (wave-reduced)
        float* lb = lds + 2048;
        for (int i = tid; i < 512; i += 256) lds[i] = qw[i];
        if (tid == 0) *lb = 0.f;
        __syncthreads();
        const float* wr = Wq + tid * 512;
        float acc = 0.f;
        for (int d = 0; d < 512; ++d) acc = fmaf(wr[d], lds[d], acc);
        ws[OFF_WQQ + tid] = acc;
        float pb = fmaf(bq[tid], lds[tid], bq[tid + 256] * lds[tid + 256]);
#pragma unroll
        for (int m = 1; m < 64; m <<= 1) pb += __shfl_xor(pb, m);
        if ((tid & 63) == 0) atomicAdd(lb, pb);
        __syncthreads();
        if (tid == 0) ws[OFF_BQQ] = *lb;
    } else if (bid == 193) {
        // cbias[h] = (bq+bp)@Wo + bo ; 4 partials per h, LDS-reduced
        const int h = tid & 63, part = tid >> 6;
        float acc = 0.f;
        for (int d = part * 128; d < part * 128 + 128; ++d)
            acc = fmaf(bq[d] + bp[d], Wo[d * 64 + h], acc);
        lds[part * 64 + h] = acc;
        __syncthreads();
        if (tid < 64)
            ws[OFF_CBIAS + tid] = bo[tid] + lds[tid] + lds[64 + tid] +
                                  lds[128 + tid] + lds[192 + tid];
    } else {
        // zero s_x + t_sum
        for (int i = tid; i < 2056; i += 256) ws[OFF_SX + i] = 0.f;
    }
}

// ---------------- K1: stream x, reduce s_x / t_sum -----------------------
__global__ __launch_bounds__(256) void k_phase1(
    const float* __restrict__ x, float* __restrict__ ws)
{
    const int tid  = threadIdx.x;
    const int lane = tid & 63;
    const int wave = tid >> 6;
    const int quad = lane >> 4;
    const int l15  = lane & 15;
    __shared__ float lacc[256];
    __shared__ float ltsum;

    floatx4 wv[4];
#pragma unroll
    for (int j = 0; j < 4; ++j)
        wv[j] = *(const floatx4*)(ws + OFF_WQQ + j * 64 + l15 * 4);
    const float bqq = ws[OFF_BQQ];

    const int vb = blockIdx.x;
    const int b = vb >> 7;
    const int rbase = (vb & 127) * 128;
    lacc[tid] = 0.f;
    if (tid == 0) ltsum = 0.f;
    __syncthreads();

    const float* xb = x + (size_t)b * NN * CC;
    const int r0 = rbase + wave * 32 + quad;   // rows r0 + 4*it
    floatx4 accs[4];
#pragma unroll
    for (int j = 0; j < 4; ++j)
#pragma unroll
        for (int k = 0; k < 4; ++k) accs[j][k] = 0.f;
    float ts = 0.f;

#pragma unroll 2
    for (int it = 0; it < 8; ++it) {
        const float* xr = xb + (size_t)(r0 + it * 4) * CC + l15 * 4;
        const floatx4 x0 = *(const floatx4*)(xr);
        const floatx4 x1 = *(const floatx4*)(xr + 64);
        const floatx4 x2 = *(const floatx4*)(xr + 128);
        const floatx4 x3 = *(const floatx4*)(xr + 192);
        float p = 0.f;
#pragma unroll
        for (int k = 0; k < 4; ++k) {
            p = fmaf(x0[k], wv[0][k], p);
            p = fmaf(x1[k], wv[1][k], p);
            p = fmaf(x2[k], wv[2][k], p);
            p = fmaf(x3[k], wv[3][k], p);
        }
        p += __shfl_xor(p, 1);
        p += __shfl_xor(p, 2);
        p += __shfl_xor(p, 4);
        p += __shfl_xor(p, 8);
        const float t = SCALE_F * (p + bqq);
        ts += t;
#pragma unroll
        for (int k = 0; k < 4; ++k) {
            accs[0][k] = fmaf(t, x0[k], accs[0][k]);
            accs[1][k] = fmaf(t, x1[k], accs[1][k]);
            accs[2][k] = fmaf(t, x2[k], accs[2][k]);
            accs[3][k] = fmaf(t, x3[k], accs[3][k]);
        }
    }

#pragma unroll
    for (int j = 0; j < 4; ++j)
#pragma unroll
        for (int k = 0; k < 4; ++k) {
            float v = accs[j][k];
            v += __shfl_xor(v, 16);
            v += __shfl_xor(v, 32);
            if (quad == 0) atomicAdd(&lacc[j * 64 + l15 * 4 + k], v);
        }
    if (l15 == 0) atomicAdd(&ltsum, ts);
    __syncthreads();
    atomicAdd(&ws[OFF_SX + b * 256 + tid], lacc[tid]);
    if (tid == 0) atomicAdd(&ws[OFF_TSUM + b], ltsum);
}

// ---------------- K2a: aw[b,d] = s_x[b]@Wq[:,d] + tsum[b]*bq[d] ------------
// grid (8, 8). IDEMPOTENT (pure fn of ws inputs) -> safe to launch twice.
__global__ __launch_bounds__(256) void k_aw(
    const float* __restrict__ Wq, const float* __restrict__ bq,
    float* __restrict__ ws)
{
    const int tid = threadIdx.x;
    const int b = blockIdx.y;
    const int dl = tid & 63, part = tid >> 6;
    const int d = blockIdx.x * 64 + dl;
    __shared__ float lsx[256];
    __shared__ float lred[256];
    __shared__ float lts;
    lsx[tid] = ws[OFF_SX + b * 256 + tid];
    if (tid == 0) lts = ws[OFF_TSUM + b];
    __syncthreads();

    const int c0 = part * 64;
    float a0 = 0.f, a1 = 0.f, a2 = 0.f, a3 = 0.f;
    for (int c = c0; c < c0 + 64; c += 4) {
        a0 = fmaf(lsx[c + 0], Wq[(c + 0) * 512 + d], a0);
        a1 = fmaf(lsx[c + 1], Wq[(c + 1) * 512 + d], a1);
        a2 = fmaf(lsx[c + 2], Wq[(c + 2) * 512 + d], a2);
        a3 = fmaf(lsx[c + 3], Wq[(c + 3) * 512 + d], a3);
    }
    lred[tid] = ((a0 + a1) + (a2 + a3));
    __syncthreads();
    if (tid < 64) {
        const float s = lred[tid] + lred[64 + tid] + lred[128 + tid] + lred[192 + tid];
        const int dd = blockIdx.x * 64 + tid;
        ws[OFF_AW + b * 512 + dd] = lts * bq[dd] + s;
    }
}

// ---------------- K2b: W_effT (bf16) + b_eff -- h-vectorized v2 ------------
// grid (256, 8): blockIdx.x = c, blockIdx.y = batch. IDEMPOTENT.
// thread: hq = tid&15 (h = hq*4+j, one float4 of WpWo), part = tid>>4
// (32-d slice). 96 VMEM instrs/thread (vs 384); wp reads = full 256B lines.
__global__ __launch_bounds__(256) void k_weff(
    const float* __restrict__ Wk, const float* __restrict__ bk,
    float* __restrict__ ws)
{
    const int tid = threadIdx.x;
    const int b = blockIdx.y;
    const int c = blockIdx.x;
    const int hq = tid & 15;
    const int part = tid >> 4;
    __shared__ floatx4 lr[256];
    __shared__ floatx4 lrb[256];

    const float* law = ws + OFF_AW + (size_t)b * 512;
    const float* wkr = Wk + (size_t)c * 512;
    const floatx4* wp4 = (const floatx4*)(ws + OFF_WPWO);
    const bool do_beff = (c == 0);

    floatx4 acc;
    acc[0] = acc[1] = acc[2] = acc[3] = 0.f;
    const int d0 = part * 32;
    for (int d = d0; d < d0 + 32; ++d) {
        const float g = wkr[d] * law[d];
        const floatx4 w = wp4[d * 16 + hq];
        acc[0] = fmaf(g, w[0], acc[0]);
        acc[1] = fmaf(g, w[1], acc[1]);
        acc[2] = fmaf(g, w[2], acc[2]);
        acc[3] = fmaf(g, w[3], acc[3]);
    }
    lr[tid] = acc;

    if (do_beff) {
        floatx4 bacc;
        bacc[0] = bacc[1] = bacc[2] = bacc[3] = 0.f;
        for (int d = d0; d < d0 + 32; ++d) {
            const float gb = bk[d] * law[d];
            const floatx4 w = wp4[d * 16 + hq];
            bacc[0] = fmaf(gb, w[0], bacc[0]);
            bacc[1] = fmaf(gb, w[1], bacc[1]);
            bacc[2] = fmaf(gb, w[2], bacc[2]);
            bacc[3] = fmaf(gb, w[3], bacc[3]);
        }
        lrb[tid] = bacc;
    }
    __syncthreads();

    // tree reduce over the 16 parts (partner = tid + s*16)
#pragma unroll
    for (int s = 8; s >= 1; s >>= 1) {
        if (part < s) {
            lr[tid] += lr[tid + s * 16];
            if (do_beff) lrb[tid] += lrb[tid + s * 16];
        }
        __syncthreads();
    }

    if (tid < 16) {
        const floatx4 wq = *(const floatx4*)(ws + OFF_WQWO + c * 64 + tid * 4);
        const floatx4 v = lr[tid];
        ushort_t* wt = (ushort_t*)(ws + OFF_WEFFT) + (size_t)b * (HH * CC);
        wt[(size_t)(tid * 4 + 0) * CC + c] = f2bf(wq[0] + v[0]);
        wt[(size_t)(tid * 4 + 1) * CC + c] = f2bf(wq[1] + v[1]);
        wt[(size_t)(tid * 4 + 2) * CC + c] = f2bf(wq[2] + v[2]);
        wt[(size_t)(tid * 4 + 3) * CC + c] = f2bf(wq[3] + v[3]);
        if (do_beff) {
            const floatx4 cb = *(const floatx4*)(ws + OFF_CBIAS + tid * 4);
            const floatx4 vb = lrb[tid];
            *(floatx4*)(ws + OFF_BEFF + b * 64 + tid * 4) = cb + vb;
        }
    }
}

// ---------------- K3: out = x @ W_eff + b_eff  (MFMA bf16) -----------------
// R2/R3 version (pre-hoist). grid 1024: vb>>7 = batch, vb&127 = row-tile;
// TWO 64-row tiles per W_effT staging.
__global__ __launch_bounds__(256) void k_out(
    const float* __restrict__ x, const float* __restrict__ ws,
    float* __restrict__ out)
{
    const int tid  = threadIdx.x;
    const int lane = tid & 63;
    const int wave = tid >> 6;
    const int quad = lane >> 4;
    const int l15  = lane & 15;
    __shared__ __align__(16) ushort_t lwt[64 * 264];

    const int vb = blockIdx.x;
    const int b = vb >> 7;
    const int rt0 = vb & 127;
    const ushort_t* wt = (const ushort_t*)(ws + OFF_WEFFT) + (size_t)b * (HH * CC);
    for (int o = tid; o < 2048; o += 256) {
        const int h = o >> 5, seg = o & 31;
        *(short8*)(lwt + h * 264 + seg * 8) = *(const short8*)(wt + h * 256 + seg * 8);
    }
    __syncthreads();

    const float* beff = ws + OFF_BEFF + b * 64;
    float bias[4];
#pragma unroll
    for (int ht = 0; ht < 4; ++ht) bias[ht] = beff[ht * 16 + l15];

#pragma unroll
    for (int s = 0; s < 2; ++s) {
        const int row0 = (rt0 + s * 128) * 64 + wave * 16;
        const float* xr = x + ((size_t)b * NN + row0 + l15) * CC + quad * 8;
        short8 afrag[8];
#pragma unroll
        for (int kk = 0; kk < 8; ++kk) {
            const floatx4 u0 = *(const floatx4*)(xr + kk * 32);
            const floatx4 u1 = *(const floatx4*)(xr + kk * 32 + 4);
            short8 t;
            t[0] = (short)f2bf(u0[0]); t[1] = (short)f2bf(u0[1]);
            t[2] = (short)f2bf(u0[2]); t[3] = (short)f2bf(u0[3]);
            t[4] = (short)f2bf(u1[0]); t[5] = (short)f2bf(u1[1]);
            t[6] = (short)f2bf(u1[2]); t[7] = (short)f2bf(u1[3]);
            afrag[kk] = t;
        }
        floatx4 acc[4];
#pragma unroll
        for (int ht = 0; ht < 4; ++ht)
#pragma unroll
            for (int r = 0; r < 4; ++r) acc[ht][r] = 0.f;

#pragma unroll
        for (int kk = 0; kk < 8; ++kk)
#pragma unroll
            for (int ht = 0; ht < 4; ++ht) {
                const short8 bf =
                    *(const short8*)(lwt + (ht * 16 + l15) * 264 + quad * 8 + kk * 32);
                acc[ht] = __builtin_amdgcn_mfma_f32_16x16x32_bf16(
                    afrag[kk], bf, acc[ht], 0, 0, 0);
            }

#pragma unroll
        for (int ht = 0; ht < 4; ++ht) {
            const int h = ht * 16 + l15;
#pragma unroll
            for (int r = 0; r < 4; ++r) {
                const int row = row0 + quad * 4 + r;
                out[((size_t)b * NN + row) * HH + h] = acc[ht][r] + bias[ht];
            }
        }
    }
}

extern "C" void kernel_launch(void* const* d_in, const int* in_sizes, int n_in,
                              void* d_out, int out_size, void* d_ws, size_t ws_size,
                              hipStream_t stream) {
    const float* x  = (const float*)d_in[0];
    const float* Wq = (const float*)d_in[1];
    const float* bq = (const float*)d_in[2];
    const float* Wk = (const float*)d_in[3];
    const float* bk = (const float*)d_in[4];
    const float* qw = (const float*)d_in[5];
    const float* Wp = (const float*)d_in[6];
    const float* bp = (const float*)d_in[7];
    const float* Wo = (const float*)d_in[8];
    const float* bo = (const float*)d_in[9];
    float* ws  = (float*)d_ws;
    float* out = (float*)d_out;

    hipLaunchKernelGGL(k_prep,   dim3(195),    dim3(256), 0, stream,
                       Wq, bq, qw, Wp, bp, Wo, bo, ws);
    hipLaunchKernelGGL(k_phase1, dim3(1024),   dim3(256), 0, stream, x, ws);
    // aw/weff are idempotent: double-launch = direct dur attribution
    // (family cost ≈ (dur_us - 206) / 2; R7 drops the duplicates)
    hipLaunchKernelGGL(k_aw,     dim3(8, 8),   dim3(256), 0, stream, Wq, bq, ws);
    hipLaunchKernelGGL(k_aw,     dim3(8, 8),   dim3(256), 0, stream, Wq, bq, ws);
    hipLaunchKernelGGL(k_weff,   dim3(256, 8), dim3(256), 0, stream, Wk, bk, ws);
    hipLaunchKernelGGL(k_weff,   dim3(256, 8), dim3(256), 0, stream, Wk, bk, ws);
    hipLaunchKernelGGL(k_out,    dim3(1024),   dim3(256), 0, stream, x, ws, out);
}